// Round 15
// baseline (123.951 us; speedup 1.0000x reference)
//
#include <hip/hip_runtime.h>
#include <hip/hip_bf16.h>
#include <math.h>

// Shapes: B=1, N=256, C=128, H=4, CH=32
// Round 15: k_projg reverted to round-11 form (best measured). b2t layout
// changed to [h][i][j] (j contiguous) so k_attn's bias reads are float4
// (128 scalar loads/thread -> 32 vector loads). k_attn otherwise UNCHANGED.

typedef __attribute__((ext_vector_type(8))) short short8;   // 8 bf16 (4 VGPRs)
typedef __attribute__((ext_vector_type(4))) short short4v;  // 4 bf16 (2 VGPRs)
typedef __attribute__((ext_vector_type(4))) float f32x4;

__device__ __forceinline__ unsigned short f2bf(float f) {
  __hip_bfloat16 b = __float2bfloat16(f);
  return __builtin_bit_cast(unsigned short, b);
}
__device__ __forceinline__ float bf2f(unsigned short u) {
  return __uint_as_float(((unsigned int)u) << 16);
}

__device__ __forceinline__ f32x4 mfma16(short8 a, short8 b, f32x4 c) {
  return __builtin_amdgcn_mfma_f32_16x16x32_bf16(a, b, c, 0, 0, 0);
}

// ---------------- K1: LayerNorm (16-lane groups) + fused weight-conv blocks ----------------
__global__ __launch_bounds__(256) void k_ln(const float* __restrict__ act,
                                            const float* __restrict__ ln_g,
                                            const float* __restrict__ ln_b,
                                            const float* __restrict__ wq,
                                            const float* __restrict__ wk,
                                            const float* __restrict__ wv,
                                            const float* __restrict__ wg,
                                            const float* __restrict__ w2d,
                                            const float* __restrict__ wo,
                                            const float* __restrict__ mask,
                                            unsigned short* __restrict__ lnxb,
                                            unsigned short* __restrict__ Wt4,
                                            unsigned short* __restrict__ Wto,
                                            float* __restrict__ maskT) {
  int t = threadIdx.x;
  if (blockIdx.x >= 4096) {
    int idx = (blockIdx.x - 4096) * 256 + t;
    if (idx < 65536) {
      int n = idx >> 7, k = idx & 127;
      const float* ws = (n < 128) ? wq : (n < 256) ? wk : (n < 384) ? wv : wg;
      Wt4[idx] = f2bf(ws[k * 128 + (n & 127)]);
    } else if (idx < 73728) {
      int j = idx - 65536;               // Wt4 rows 512..575
      int r = j >> 7, k = j & 127;
      Wt4[idx] = (r < 4) ? f2bf(w2d[k * 4 + r]) : (unsigned short)0;
    } else if (idx < 90112) {
      int j = idx - 73728;
      int n = j >> 7, k = j & 127;
      Wto[j] = f2bf(wo[k * 128 + n]);
    } else if (idx < 155648) {
      int j2 = idx - 90112;
      int mi = j2 & 255, jj = j2 >> 8;   // coalesced read of mask row jj
      maskT[mi * 256 + jj] = 1e9f * (mask[jj * 256 + mi] - 1.0f);
    }
    return;
  }
  int grp = t >> 4, l16 = t & 15;
  int row = blockIdx.x * 16 + grp;
  int mm = row >> 8, ii = row & 255;
  const float4* a = (const float4*)(act + ((size_t)(ii * 256 + mm)) * 128);
  float4 v0 = a[l16 * 2], v1 = a[l16 * 2 + 1];
  float s = (v0.x + v0.y) + (v0.z + v0.w) + (v1.x + v1.y) + (v1.z + v1.w);
  #pragma unroll
  for (int off = 1; off < 16; off <<= 1) s += __shfl_xor(s, off, 64);
  float mean = s * (1.f / 128.f);
  float e[8] = {v0.x - mean, v0.y - mean, v0.z - mean, v0.w - mean,
                v1.x - mean, v1.y - mean, v1.z - mean, v1.w - mean};
  float vs = (e[0]*e[0] + e[1]*e[1]) + (e[2]*e[2] + e[3]*e[3]) +
             (e[4]*e[4] + e[5]*e[5]) + (e[6]*e[6] + e[7]*e[7]);
  #pragma unroll
  for (int off = 1; off < 16; off <<= 1) vs += __shfl_xor(vs, off, 64);
  float rstd = rsqrtf(vs * (1.f / 128.f) + 1e-5f);
  const float4* gp = (const float4*)ln_g;
  const float4* bp = (const float4*)ln_b;
  float4 g0 = gp[l16 * 2], g1 = gp[l16 * 2 + 1];
  float4 b0 = bp[l16 * 2], b1 = bp[l16 * 2 + 1];
  short8 o;
  o[0] = (short)f2bf(e[0] * rstd * g0.x + b0.x);
  o[1] = (short)f2bf(e[1] * rstd * g0.y + b0.y);
  o[2] = (short)f2bf(e[2] * rstd * g0.z + b0.z);
  o[3] = (short)f2bf(e[3] * rstd * g0.w + b0.w);
  o[4] = (short)f2bf(e[4] * rstd * g1.x + b1.x);
  o[5] = (short)f2bf(e[5] * rstd * g1.y + b1.y);
  o[6] = (short)f2bf(e[6] * rstd * g1.z + b1.z);
  o[7] = (short)f2bf(e[7] * rstd * g1.w + b1.w);
  *(short8*)(lnxb + (size_t)row * 128 + l16 * 8) = o;
}

// ---------------- K2: fused q/k/v/g/b2 projection, bf16 MFMA, D[n,R] (round-11 form) ----------------
// grid (512, 9): y=0..7 -> q/k/v/g; y=8 -> pair-bias b2t[h][R] (coalesced).
__global__ __launch_bounds__(256) void k_projg(const unsigned short* __restrict__ A,
                                               const unsigned short* __restrict__ Bt,
                                               const float* __restrict__ bg,
                                               unsigned short* __restrict__ qb,
                                               unsigned short* __restrict__ kb,
                                               unsigned short* __restrict__ vb,
                                               unsigned short* __restrict__ sgb,
                                               float* __restrict__ b2t) {
  __shared__ unsigned short As[128 * 40];
  __shared__ unsigned short Bs[64 * 40];
  int t = threadIdx.x;
  int m0 = blockIdx.x * 128, n0 = blockIdx.y * 64;
  int w = t >> 6, l = t & 63, g = l >> 4, li = l & 15;
  int wr = w >> 1, wc = w & 1;
  f32x4 acc[4][2] = {};
  for (int s = 0; s < 4; ++s) {
    int k0 = s * 32;
    __syncthreads();
    {
      int row = t >> 1, kl = (t & 1) * 16;
      const short8* src = (const short8*)(A + (size_t)(m0 + row) * 128 + k0 + kl);
      *(short8*)&As[row * 40 + kl]     = src[0];
      *(short8*)&As[row * 40 + kl + 8] = src[1];
      int bn = t >> 2, bk = (t & 3) * 8;
      *(short8*)&Bs[bn * 40 + bk] = *(const short8*)(Bt + (size_t)(n0 + bn) * 128 + k0 + bk);
    }
    __syncthreads();
    short8 af[4], bf[2];
    #pragma unroll
    for (int it = 0; it < 4; ++it)
      af[it] = *(const short8*)&As[(wr * 64 + it * 16 + li) * 40 + g * 8];
    #pragma unroll
    for (int jt = 0; jt < 2; ++jt)
      bf[jt] = *(const short8*)&Bs[(wc * 32 + jt * 16 + li) * 40 + g * 8];
    #pragma unroll
    for (int it = 0; it < 4; ++it)
      #pragma unroll
      for (int jt = 0; jt < 2; ++jt)
        acc[it][jt] = mfma16(bf[jt], af[it], acc[it][jt]);   // D[n, R]
  }
  int which = n0 >> 7;
  if (which == 4) {
    // pair-bias rows hb = wc*32+jt*16+g*4+r < 4 -> wc==0, jt==0, g==0.
    // b2t[h][R] layout (R = i*256+j): coalesced store over li.
    if (wc == 0 && g == 0) {
      #pragma unroll
      for (int it = 0; it < 4; ++it) {
        int R = m0 + wr * 64 + it * 16 + li;
        #pragma unroll
        for (int r = 0; r < 4; ++r)
          b2t[(size_t)r * 65536 + R] = acc[it][0][r];
      }
    }
    return;
  }
  const float factor = 0.17677669529663687f;  // 1/sqrt(32)
  #pragma unroll
  for (int it = 0; it < 4; ++it) {
    int R = m0 + wr * 64 + it * 16 + li;
    int mm = R >> 8, ii = R & 255;
    #pragma unroll
    for (int jt = 0; jt < 2; ++jt) {
      int nb4 = n0 + wc * 32 + jt * 16 + g * 4;   // 4 consecutive n
      int hh = (nb4 >> 5) & 3, ch = nb4 & 31;
      size_t o = ((size_t)((mm * 4 + hh) * 256 + ii)) * 32 + ch;
      short4v pk;
      if (which == 0) {
        #pragma unroll
        for (int r = 0; r < 4; ++r) pk[r] = (short)f2bf(acc[it][jt][r] * factor);
        *(short4v*)(qb + o) = pk;
      } else if (which == 1) {
        #pragma unroll
        for (int r = 0; r < 4; ++r) pk[r] = (short)f2bf(acc[it][jt][r]);
        *(short4v*)(kb + o) = pk;
      } else if (which == 2) {
        #pragma unroll
        for (int r = 0; r < 4; ++r) pk[r] = (short)f2bf(acc[it][jt][r]);
        *(short4v*)(vb + o) = pk;
      } else {
        #pragma unroll
        for (int r = 0; r < 4; ++r)
          pk[r] = (short)f2bf(1.f / (1.f + __expf(-(acc[it][jt][r] + bg[(nb4 & 127) + r]))));
        *(short4v*)(sgb + o) = pk;
      }
    }
  }
}

// ---------------- K3: attention, MFMA flash-style ----------------
// Only change vs round 9-14: b2t is [h][i][j] -> bias read is one float4
// per jt (was 4 scalar 1KB-stride loads). Softmax dataflow unchanged.
__global__ __launch_bounds__(256) void k_attn(const unsigned short* __restrict__ qb,
                                              const unsigned short* __restrict__ kb,
                                              const unsigned short* __restrict__ vb,
                                              const unsigned short* __restrict__ sgb,
                                              const float* __restrict__ b2t,
                                              const float* __restrict__ maskT,
                                              unsigned short* __restrict__ aob) {
  __shared__ unsigned short VT[32 * 264];    // V^T [c][j], pad 264 (528B stride)
  __shared__ unsigned short Pl[4 * 32 * 72]; // per-wave P [i][j], pad 72 (144B)
  __shared__ float maskls[256];
  int m = blockIdx.x >> 1, ihalf = blockIdx.x & 1, h = blockIdx.y;
  int t = threadIdx.x, w = t >> 6, l = t & 63, g = l >> 4, li = l & 15;
  int base = (m * 4 + h) << 8;
  maskls[t] = maskT[m * 256 + t];            // contiguous, precomputed
  {  // stage V^T
    const unsigned int* v32 = (const unsigned int*)(vb + (size_t)base * 32);
    #pragma unroll
    for (int p = 0; p < 16; ++p) {
      int idx = t + p * 256;
      int j = idx >> 4, cp = idx & 15;
      unsigned int u = v32[idx];
      VT[(cp * 2) * 264 + j]     = (unsigned short)(u & 0xffff);
      VT[(cp * 2 + 1) * 264 + j] = (unsigned short)(u >> 16);
    }
  }
  __syncthreads();
  int i0 = ihalf * 128 + w * 32;
  short8 qf[2];
  #pragma unroll
  for (int it = 0; it < 2; ++it)
    qf[it] = *(const short8*)(qb + ((size_t)(base + i0 + it * 16 + li)) * 32 + g * 8);
  float mst[2] = {-1e30f, -1e30f};
  float lst[2] = {0.f, 0.f};
  f32x4 oacc[2][2] = {};
  const float* b2 = b2t + (size_t)h * 65536;
  unsigned short* Pw = Pl + w * 32 * 72;
  for (int jc = 0; jc < 4; ++jc) {
    int j0 = jc * 64;
    f32x4 sacc[4][2];
    #pragma unroll
    for (int jt = 0; jt < 4; ++jt) {
      short8 kf = *(const short8*)(kb + ((size_t)(base + j0 + jt * 16 + li)) * 32 + g * 8);
      #pragma unroll
      for (int it = 0; it < 2; ++it) {
        f32x4 z = {0.f, 0.f, 0.f, 0.f};
        sacc[jt][it] = mfma16(kf, qf[it], z);
      }
    }
    #pragma unroll
    for (int it = 0; it < 2; ++it) {
      int ic = i0 + it * 16 + li;
      float s[16];
      float cmax = -1e30f;
      #pragma unroll
      for (int jt = 0; jt < 4; ++jt) {
        int jb = j0 + jt * 16 + g * 4;
        f32x4 mk = *(const f32x4*)&maskls[jb];
        f32x4 bv = *(const f32x4*)(b2 + (size_t)ic * 256 + jb);   // [i][j]: float4
        #pragma unroll
        for (int r = 0; r < 4; ++r) {
          float sv = sacc[jt][it][r] + bv[r] + mk[r];
          s[jt * 4 + r] = sv;
          cmax = fmaxf(cmax, sv);
        }
      }
      cmax = fmaxf(cmax, __shfl_xor(cmax, 16));
      cmax = fmaxf(cmax, __shfl_xor(cmax, 32));
      float mnew = fmaxf(mst[it], cmax);
      float fac = __expf(mst[it] - mnew);
      mst[it] = mnew;
      lst[it] *= fac;
      oacc[0][it] *= fac;
      oacc[1][it] *= fac;
      float psum = 0.f;
      #pragma unroll
      for (int jt = 0; jt < 4; ++jt) {
        float p0 = __expf(s[jt * 4 + 0] - mnew);
        float p1 = __expf(s[jt * 4 + 1] - mnew);
        float p2 = __expf(s[jt * 4 + 2] - mnew);
        float p3 = __expf(s[jt * 4 + 3] - mnew);
        psum += p0 + p1 + p2 + p3;
        short4v pk;
        pk.x = (short)f2bf(p0); pk.y = (short)f2bf(p1);
        pk.z = (short)f2bf(p2); pk.w = (short)f2bf(p3);
        *(short4v*)&Pw[(it * 16 + li) * 72 + jt * 16 + g * 4] = pk;
      }
      lst[it] += psum;
    }
    // P is per-wave private; fence orders ds_writes before ds_reads (in-order per wave)
    asm volatile("" ::: "memory");
    #pragma unroll
    for (int ks = 0; ks < 2; ++ks) {
      short8 vf0 = *(const short8*)&VT[li * 264        + j0 + ks * 32 + g * 8];
      short8 vf1 = *(const short8*)&VT[(16 + li) * 264 + j0 + ks * 32 + g * 8];
      #pragma unroll
      for (int it = 0; it < 2; ++it) {
        short8 pf = *(const short8*)&Pw[(it * 16 + li) * 72 + ks * 32 + g * 8];
        oacc[0][it] = mfma16(vf0, pf, oacc[0][it]);
        oacc[1][it] = mfma16(vf1, pf, oacc[1][it]);
      }
    }
    asm volatile("" ::: "memory");
  }
  #pragma unroll
  for (int it = 0; it < 2; ++it) {
    float lt = lst[it];
    lt += __shfl_xor(lt, 16);
    lt += __shfl_xor(lt, 32);
    float inv = 1.f / lt;
    int ic = i0 + it * 16 + li;
    #pragma unroll
    for (int ct = 0; ct < 2; ++ct) {
      int c0 = ct * 16 + g * 4;
      const unsigned short* grow = sgb + ((size_t)(base + ic)) * 32 + c0;
      ushort4 gu = *(const ushort4*)grow;
      ushort4 ov;
      ov.x = f2bf(oacc[ct][it][0] * inv * bf2f(gu.x));
      ov.y = f2bf(oacc[ct][it][1] * inv * bf2f(gu.y));
      ov.z = f2bf(oacc[ct][it][2] * inv * bf2f(gu.z));
      ov.w = f2bf(oacc[ct][it][3] * inv * bf2f(gu.w));
      *(ushort4*)&aob[((size_t)(ic * 256 + m)) * 128 + h * 32 + c0] = ov;
    }
  }
}

// ---------------- K4: output projection, bf16 MFMA, D[n,R] (round-11 form) ----------------
__global__ __launch_bounds__(256) void k_outg(const unsigned short* __restrict__ A,
                                              const unsigned short* __restrict__ Bt,
                                              const float* __restrict__ bo,
                                              float* __restrict__ out) {
  __shared__ unsigned short As[128 * 40];
  __shared__ unsigned short Bs[64 * 40];
  int t = threadIdx.x;
  int m0 = blockIdx.x * 128, n0 = blockIdx.y * 64;
  int w = t >> 6, l = t & 63, g = l >> 4, li = l & 15;
  int wr = w >> 1, wc = w & 1;
  f32x4 acc[4][2] = {};
  for (int s = 0; s < 4; ++s) {
    int k0 = s * 32;
    __syncthreads();
    {
      int row = t >> 1, kl = (t & 1) * 16;
      const short8* src = (const short8*)(A + (size_t)(m0 + row) * 128 + k0 + kl);
      *(short8*)&As[row * 40 + kl]     = src[0];
      *(short8*)&As[row * 40 + kl + 8] = src[1];
      int bn = t >> 2, bk = (t & 3) * 8;
      *(short8*)&Bs[bn * 40 + bk] = *(const short8*)(Bt + (size_t)(n0 + bn) * 128 + k0 + bk);
    }
    __syncthreads();
    short8 af[4], bf[2];
    #pragma unroll
    for (int it = 0; it < 4; ++it)
      af[it] = *(const short8*)&As[(wr * 64 + it * 16 + li) * 40 + g * 8];
    #pragma unroll
    for (int jt = 0; jt < 2; ++jt)
      bf[jt] = *(const short8*)&Bs[(wc * 32 + jt * 16 + li) * 40 + g * 8];
    #pragma unroll
    for (int it = 0; it < 4; ++it)
      #pragma unroll
      for (int jt = 0; jt < 2; ++jt)
        acc[it][jt] = mfma16(bf[jt], af[it], acc[it][jt]);   // D[n, R]
  }
  #pragma unroll
  for (int it = 0; it < 4; ++it) {
    int R = m0 + wr * 64 + it * 16 + li;
    #pragma unroll
    for (int jt = 0; jt < 2; ++jt) {
      int nb4 = n0 + wc * 32 + jt * 16 + g * 4;
      float4 o;
      o.x = acc[it][jt][0] + bo[nb4 + 0];
      o.y = acc[it][jt][1] + bo[nb4 + 1];
      o.z = acc[it][jt][2] + bo[nb4 + 2];
      o.w = acc[it][jt][3] + bo[nb4 + 3];
      *(float4*)(out + (size_t)R * 128 + nb4) = o;
    }
  }
}

extern "C" void kernel_launch(void* const* d_in, const int* in_sizes, int n_in,
                              void* d_out, int out_size, void* d_ws, size_t ws_size,
                              hipStream_t stream) {
  const float* act  = (const float*)d_in[0];
  const float* mask = (const float*)d_in[1];
  const float* ln_g = (const float*)d_in[2];
  const float* ln_b = (const float*)d_in[3];
  const float* wq   = (const float*)d_in[4];
  const float* wk   = (const float*)d_in[5];
  const float* wv   = (const float*)d_in[6];
  const float* w2d  = (const float*)d_in[7];
  const float* wg   = (const float*)d_in[8];
  const float* bg   = (const float*)d_in[9];
  const float* wo   = (const float*)d_in[10];
  const float* bo   = (const float*)d_in[11];

  char* p = (char*)d_ws;
  unsigned short* lnxb  = (unsigned short*)p;  p += (size_t)8388608 * 2;   // [65536][128] bf16
  float*          b2t   = (float*)p;           p += (size_t)262144 * 4;    // [4][i*256+j] f32
  unsigned short* qb    = (unsigned short*)p;  p += (size_t)8388608 * 2;   // [262144][32] bf16
  unsigned short* kb    = (unsigned short*)p;  p += (size_t)8388608 * 2;
  unsigned short* vb    = (unsigned short*)p;  p += (size_t)8388608 * 2;
  unsigned short* sgb   = (unsigned short*)p;  p += (size_t)8388608 * 2;   // gate, bf16
  unsigned short* aob   = (unsigned short*)p;  p += (size_t)8388608 * 2;   // [65536][128] bf16
  unsigned short* Wt4   = (unsigned short*)p;  p += (size_t)73728 * 2;     // [576][128] bf16
  unsigned short* Wto   = (unsigned short*)p;  p += (size_t)16384 * 2;
  float*          maskT = (float*)p;           p += (size_t)65536 * 4;     // [m][j] * 1e9
  float* out = (float*)d_out;

  hipLaunchKernelGGL(k_ln,    dim3(4704),   dim3(256), 0, stream,
                     act, ln_g, ln_b, wq, wk, wv, wg, w2d, wo, mask, lnxb, Wt4, Wto, maskT);
  hipLaunchKernelGGL(k_projg, dim3(512, 9), dim3(256), 0, stream, lnxb, Wt4, bg, qb, kb, vb, sgb, b2t);
  hipLaunchKernelGGL(k_attn,  dim3(512, 4), dim3(256), 0, stream, qb, kb, vb, sgb, b2t, maskT, aob);
  hipLaunchKernelGGL(k_outg,  dim3(512, 2), dim3(256), 0, stream, aob, Wto, bo, out);
}

// Round 16
// 95.561 us; speedup vs baseline: 1.2971x; 1.2971x over previous
//
#include <hip/hip_runtime.h>
#include <hip/hip_bf16.h>
#include <math.h>

// Shapes: B=1, N=256, C=128, H=4, CH=32
// Round 16 = exact revert to round 11 (best measured: 95.7 us).
// k_attn: coalesced scalar b2 reads ([h][j][i] layout), online-max softmax,
// per-wave P in LDS, no barriers in K-loop. k_projg: (512,9) barrier-staged
// D[n,R]. k_ln: 16-lane groups + fused weight conversion. k_outg: D[n,R].

typedef __attribute__((ext_vector_type(8))) short short8;   // 8 bf16 (4 VGPRs)
typedef __attribute__((ext_vector_type(4))) short short4v;  // 4 bf16 (2 VGPRs)
typedef __attribute__((ext_vector_type(4))) float f32x4;

__device__ __forceinline__ unsigned short f2bf(float f) {
  __hip_bfloat16 b = __float2bfloat16(f);
  return __builtin_bit_cast(unsigned short, b);
}
__device__ __forceinline__ float bf2f(unsigned short u) {
  return __uint_as_float(((unsigned int)u) << 16);
}

__device__ __forceinline__ f32x4 mfma16(short8 a, short8 b, f32x4 c) {
  return __builtin_amdgcn_mfma_f32_16x16x32_bf16(a, b, c, 0, 0, 0);
}

// ---------------- K1: LayerNorm (16-lane groups) + fused weight-conv blocks ----------------
__global__ __launch_bounds__(256) void k_ln(const float* __restrict__ act,
                                            const float* __restrict__ ln_g,
                                            const float* __restrict__ ln_b,
                                            const float* __restrict__ wq,
                                            const float* __restrict__ wk,
                                            const float* __restrict__ wv,
                                            const float* __restrict__ wg,
                                            const float* __restrict__ w2d,
                                            const float* __restrict__ wo,
                                            const float* __restrict__ mask,
                                            unsigned short* __restrict__ lnxb,
                                            unsigned short* __restrict__ Wt4,
                                            unsigned short* __restrict__ Wto,
                                            float* __restrict__ maskT) {
  int t = threadIdx.x;
  if (blockIdx.x >= 4096) {
    int idx = (blockIdx.x - 4096) * 256 + t;
    if (idx < 65536) {
      int n = idx >> 7, k = idx & 127;
      const float* ws = (n < 128) ? wq : (n < 256) ? wk : (n < 384) ? wv : wg;
      Wt4[idx] = f2bf(ws[k * 128 + (n & 127)]);
    } else if (idx < 73728) {
      int j = idx - 65536;               // Wt4 rows 512..575
      int r = j >> 7, k = j & 127;
      Wt4[idx] = (r < 4) ? f2bf(w2d[k * 4 + r]) : (unsigned short)0;
    } else if (idx < 90112) {
      int j = idx - 73728;
      int n = j >> 7, k = j & 127;
      Wto[j] = f2bf(wo[k * 128 + n]);
    } else if (idx < 155648) {
      int j2 = idx - 90112;
      int mi = j2 & 255, jj = j2 >> 8;   // coalesced read of mask row jj
      maskT[mi * 256 + jj] = 1e9f * (mask[jj * 256 + mi] - 1.0f);
    }
    return;
  }
  int grp = t >> 4, l16 = t & 15;
  int row = blockIdx.x * 16 + grp;
  int mm = row >> 8, ii = row & 255;
  const float4* a = (const float4*)(act + ((size_t)(ii * 256 + mm)) * 128);
  float4 v0 = a[l16 * 2], v1 = a[l16 * 2 + 1];
  float s = (v0.x + v0.y) + (v0.z + v0.w) + (v1.x + v1.y) + (v1.z + v1.w);
  #pragma unroll
  for (int off = 1; off < 16; off <<= 1) s += __shfl_xor(s, off, 64);
  float mean = s * (1.f / 128.f);
  float e[8] = {v0.x - mean, v0.y - mean, v0.z - mean, v0.w - mean,
                v1.x - mean, v1.y - mean, v1.z - mean, v1.w - mean};
  float vs = (e[0]*e[0] + e[1]*e[1]) + (e[2]*e[2] + e[3]*e[3]) +
             (e[4]*e[4] + e[5]*e[5]) + (e[6]*e[6] + e[7]*e[7]);
  #pragma unroll
  for (int off = 1; off < 16; off <<= 1) vs += __shfl_xor(vs, off, 64);
  float rstd = rsqrtf(vs * (1.f / 128.f) + 1e-5f);
  const float4* gp = (const float4*)ln_g;
  const float4* bp = (const float4*)ln_b;
  float4 g0 = gp[l16 * 2], g1 = gp[l16 * 2 + 1];
  float4 b0 = bp[l16 * 2], b1 = bp[l16 * 2 + 1];
  short8 o;
  o[0] = (short)f2bf(e[0] * rstd * g0.x + b0.x);
  o[1] = (short)f2bf(e[1] * rstd * g0.y + b0.y);
  o[2] = (short)f2bf(e[2] * rstd * g0.z + b0.z);
  o[3] = (short)f2bf(e[3] * rstd * g0.w + b0.w);
  o[4] = (short)f2bf(e[4] * rstd * g1.x + b1.x);
  o[5] = (short)f2bf(e[5] * rstd * g1.y + b1.y);
  o[6] = (short)f2bf(e[6] * rstd * g1.z + b1.z);
  o[7] = (short)f2bf(e[7] * rstd * g1.w + b1.w);
  *(short8*)(lnxb + (size_t)row * 128 + l16 * 8) = o;
}

// ---------------- K2: fused q/k/v/g/b2 projection, bf16 MFMA, D[n,R] ----------------
// grid (512, 9): y=0..7 -> q/k/v/g; y=8 -> pair-bias b2t (fp32, [h][j][i]).
__global__ __launch_bounds__(256) void k_projg(const unsigned short* __restrict__ A,
                                               const unsigned short* __restrict__ Bt,
                                               const float* __restrict__ bg,
                                               unsigned short* __restrict__ qb,
                                               unsigned short* __restrict__ kb,
                                               unsigned short* __restrict__ vb,
                                               unsigned short* __restrict__ sgb,
                                               float* __restrict__ b2t) {
  __shared__ unsigned short As[128 * 40];
  __shared__ unsigned short Bs[64 * 40];
  int t = threadIdx.x;
  int m0 = blockIdx.x * 128, n0 = blockIdx.y * 64;
  int w = t >> 6, l = t & 63, g = l >> 4, li = l & 15;
  int wr = w >> 1, wc = w & 1;
  f32x4 acc[4][2] = {};
  for (int s = 0; s < 4; ++s) {
    int k0 = s * 32;
    __syncthreads();
    {
      int row = t >> 1, kl = (t & 1) * 16;
      const short8* src = (const short8*)(A + (size_t)(m0 + row) * 128 + k0 + kl);
      *(short8*)&As[row * 40 + kl]     = src[0];
      *(short8*)&As[row * 40 + kl + 8] = src[1];
      int bn = t >> 2, bk = (t & 3) * 8;
      *(short8*)&Bs[bn * 40 + bk] = *(const short8*)(Bt + (size_t)(n0 + bn) * 128 + k0 + bk);
    }
    __syncthreads();
    short8 af[4], bf[2];
    #pragma unroll
    for (int it = 0; it < 4; ++it)
      af[it] = *(const short8*)&As[(wr * 64 + it * 16 + li) * 40 + g * 8];
    #pragma unroll
    for (int jt = 0; jt < 2; ++jt)
      bf[jt] = *(const short8*)&Bs[(wc * 32 + jt * 16 + li) * 40 + g * 8];
    #pragma unroll
    for (int it = 0; it < 4; ++it)
      #pragma unroll
      for (int jt = 0; jt < 2; ++jt)
        acc[it][jt] = mfma16(bf[jt], af[it], acc[it][jt]);   // D[n, R]
  }
  int which = n0 >> 7;
  if (which == 4) {
    // pair-bias block: rows n-512 = wc*32+jt*16+g*4+r; only <4 real
    if (wc == 0 && g == 0) {
      #pragma unroll
      for (int it = 0; it < 4; ++it) {
        int R = m0 + wr * 64 + it * 16 + li;
        int mm = R >> 8, ii = R & 255;
        #pragma unroll
        for (int r = 0; r < 4; ++r)
          b2t[(size_t)r * 65536 + ii * 256 + mm] = acc[it][0][r];
      }
    }
    return;
  }
  const float factor = 0.17677669529663687f;  // 1/sqrt(32)
  #pragma unroll
  for (int it = 0; it < 4; ++it) {
    int R = m0 + wr * 64 + it * 16 + li;
    int mm = R >> 8, ii = R & 255;
    #pragma unroll
    for (int jt = 0; jt < 2; ++jt) {
      int nb4 = n0 + wc * 32 + jt * 16 + g * 4;   // 4 consecutive n
      int hh = (nb4 >> 5) & 3, ch = nb4 & 31;
      size_t o = ((size_t)((mm * 4 + hh) * 256 + ii)) * 32 + ch;
      short4v pk;
      if (which == 0) {
        #pragma unroll
        for (int r = 0; r < 4; ++r) pk[r] = (short)f2bf(acc[it][jt][r] * factor);
        *(short4v*)(qb + o) = pk;
      } else if (which == 1) {
        #pragma unroll
        for (int r = 0; r < 4; ++r) pk[r] = (short)f2bf(acc[it][jt][r]);
        *(short4v*)(kb + o) = pk;
      } else if (which == 2) {
        #pragma unroll
        for (int r = 0; r < 4; ++r) pk[r] = (short)f2bf(acc[it][jt][r]);
        *(short4v*)(vb + o) = pk;
      } else {
        #pragma unroll
        for (int r = 0; r < 4; ++r)
          pk[r] = (short)f2bf(1.f / (1.f + __expf(-(acc[it][jt][r] + bg[(nb4 & 127) + r]))));
        *(short4v*)(sgb + o) = pk;
      }
    }
  }
}

// ---------------- K3: attention, MFMA flash-style (round-11/round-9 form) ----------------
__global__ __launch_bounds__(256) void k_attn(const unsigned short* __restrict__ qb,
                                              const unsigned short* __restrict__ kb,
                                              const unsigned short* __restrict__ vb,
                                              const unsigned short* __restrict__ sgb,
                                              const float* __restrict__ b2t,
                                              const float* __restrict__ maskT,
                                              unsigned short* __restrict__ aob) {
  __shared__ unsigned short VT[32 * 264];    // V^T [c][j], pad 264 (528B stride)
  __shared__ unsigned short Pl[4 * 32 * 72]; // per-wave P [i][j], pad 72 (144B)
  __shared__ float maskls[256];
  int m = blockIdx.x >> 1, ihalf = blockIdx.x & 1, h = blockIdx.y;
  int t = threadIdx.x, w = t >> 6, l = t & 63, g = l >> 4, li = l & 15;
  int base = (m * 4 + h) << 8;
  maskls[t] = maskT[m * 256 + t];            // contiguous, precomputed
  {  // stage V^T
    const unsigned int* v32 = (const unsigned int*)(vb + (size_t)base * 32);
    #pragma unroll
    for (int p = 0; p < 16; ++p) {
      int idx = t + p * 256;
      int j = idx >> 4, cp = idx & 15;
      unsigned int u = v32[idx];
      VT[(cp * 2) * 264 + j]     = (unsigned short)(u & 0xffff);
      VT[(cp * 2 + 1) * 264 + j] = (unsigned short)(u >> 16);
    }
  }
  __syncthreads();
  int i0 = ihalf * 128 + w * 32;
  short8 qf[2];
  #pragma unroll
  for (int it = 0; it < 2; ++it)
    qf[it] = *(const short8*)(qb + ((size_t)(base + i0 + it * 16 + li)) * 32 + g * 8);
  float mst[2] = {-1e30f, -1e30f};
  float lst[2] = {0.f, 0.f};
  f32x4 oacc[2][2] = {};
  const float* b2 = b2t + (size_t)h * 65536;
  unsigned short* Pw = Pl + w * 32 * 72;
  for (int jc = 0; jc < 4; ++jc) {
    int j0 = jc * 64;
    f32x4 sacc[4][2];
    #pragma unroll
    for (int jt = 0; jt < 4; ++jt) {
      short8 kf = *(const short8*)(kb + ((size_t)(base + j0 + jt * 16 + li)) * 32 + g * 8);
      #pragma unroll
      for (int it = 0; it < 2; ++it) {
        f32x4 z = {0.f, 0.f, 0.f, 0.f};
        sacc[jt][it] = mfma16(kf, qf[it], z);
      }
    }
    #pragma unroll
    for (int it = 0; it < 2; ++it) {
      int ic = i0 + it * 16 + li;
      float s[16];
      float cmax = -1e30f;
      #pragma unroll
      for (int jt = 0; jt < 4; ++jt) {
        int jb = j0 + jt * 16 + g * 4;
        f32x4 mk = *(const f32x4*)&maskls[jb];
        #pragma unroll
        for (int r = 0; r < 4; ++r) {
          float sv = sacc[jt][it][r] + b2[(size_t)(jb + r) * 256 + ic] + mk[r];
          s[jt * 4 + r] = sv;
          cmax = fmaxf(cmax, sv);
        }
      }
      cmax = fmaxf(cmax, __shfl_xor(cmax, 16));
      cmax = fmaxf(cmax, __shfl_xor(cmax, 32));
      float mnew = fmaxf(mst[it], cmax);
      float fac = __expf(mst[it] - mnew);
      mst[it] = mnew;
      lst[it] *= fac;
      oacc[0][it] *= fac;
      oacc[1][it] *= fac;
      float psum = 0.f;
      #pragma unroll
      for (int jt = 0; jt < 4; ++jt) {
        float p0 = __expf(s[jt * 4 + 0] - mnew);
        float p1 = __expf(s[jt * 4 + 1] - mnew);
        float p2 = __expf(s[jt * 4 + 2] - mnew);
        float p3 = __expf(s[jt * 4 + 3] - mnew);
        psum += p0 + p1 + p2 + p3;
        short4v pk;
        pk.x = (short)f2bf(p0); pk.y = (short)f2bf(p1);
        pk.z = (short)f2bf(p2); pk.w = (short)f2bf(p3);
        *(short4v*)&Pw[(it * 16 + li) * 72 + jt * 16 + g * 4] = pk;
      }
      lst[it] += psum;
    }
    // P is per-wave private; fence orders ds_writes before ds_reads (in-order per wave)
    asm volatile("" ::: "memory");
    #pragma unroll
    for (int ks = 0; ks < 2; ++ks) {
      short8 vf0 = *(const short8*)&VT[li * 264        + j0 + ks * 32 + g * 8];
      short8 vf1 = *(const short8*)&VT[(16 + li) * 264 + j0 + ks * 32 + g * 8];
      #pragma unroll
      for (int it = 0; it < 2; ++it) {
        short8 pf = *(const short8*)&Pw[(it * 16 + li) * 72 + ks * 32 + g * 8];
        oacc[0][it] = mfma16(vf0, pf, oacc[0][it]);
        oacc[1][it] = mfma16(vf1, pf, oacc[1][it]);
      }
    }
    asm volatile("" ::: "memory");
  }
  #pragma unroll
  for (int it = 0; it < 2; ++it) {
    float lt = lst[it];
    lt += __shfl_xor(lt, 16);
    lt += __shfl_xor(lt, 32);
    float inv = 1.f / lt;
    int ic = i0 + it * 16 + li;
    #pragma unroll
    for (int ct = 0; ct < 2; ++ct) {
      int c0 = ct * 16 + g * 4;
      const unsigned short* grow = sgb + ((size_t)(base + ic)) * 32 + c0;
      ushort4 gu = *(const ushort4*)grow;
      ushort4 ov;
      ov.x = f2bf(oacc[ct][it][0] * inv * bf2f(gu.x));
      ov.y = f2bf(oacc[ct][it][1] * inv * bf2f(gu.y));
      ov.z = f2bf(oacc[ct][it][2] * inv * bf2f(gu.z));
      ov.w = f2bf(oacc[ct][it][3] * inv * bf2f(gu.w));
      *(ushort4*)&aob[((size_t)(ic * 256 + m)) * 128 + h * 32 + c0] = ov;
    }
  }
}

// ---------------- K4: output projection, bf16 MFMA, D[n,R] ----------------
__global__ __launch_bounds__(256) void k_outg(const unsigned short* __restrict__ A,
                                              const unsigned short* __restrict__ Bt,
                                              const float* __restrict__ bo,
                                              float* __restrict__ out) {
  __shared__ unsigned short As[128 * 40];
  __shared__ unsigned short Bs[64 * 40];
  int t = threadIdx.x;
  int m0 = blockIdx.x * 128, n0 = blockIdx.y * 64;
  int w = t >> 6, l = t & 63, g = l >> 4, li = l & 15;
  int wr = w >> 1, wc = w & 1;
  f32x4 acc[4][2] = {};
  for (int s = 0; s < 4; ++s) {
    int k0 = s * 32;
    __syncthreads();
    {
      int row = t >> 1, kl = (t & 1) * 16;
      const short8* src = (const short8*)(A + (size_t)(m0 + row) * 128 + k0 + kl);
      *(short8*)&As[row * 40 + kl]     = src[0];
      *(short8*)&As[row * 40 + kl + 8] = src[1];
      int bn = t >> 2, bk = (t & 3) * 8;
      *(short8*)&Bs[bn * 40 + bk] = *(const short8*)(Bt + (size_t)(n0 + bn) * 128 + k0 + bk);
    }
    __syncthreads();
    short8 af[4], bf[2];
    #pragma unroll
    for (int it = 0; it < 4; ++it)
      af[it] = *(const short8*)&As[(wr * 64 + it * 16 + li) * 40 + g * 8];
    #pragma unroll
    for (int jt = 0; jt < 2; ++jt)
      bf[jt] = *(const short8*)&Bs[(wc * 32 + jt * 16 + li) * 40 + g * 8];
    #pragma unroll
    for (int it = 0; it < 4; ++it)
      #pragma unroll
      for (int jt = 0; jt < 2; ++jt)
        acc[it][jt] = mfma16(bf[jt], af[it], acc[it][jt]);   // D[n, R]
  }
  #pragma unroll
  for (int it = 0; it < 4; ++it) {
    int R = m0 + wr * 64 + it * 16 + li;
    #pragma unroll
    for (int jt = 0; jt < 2; ++jt) {
      int nb4 = n0 + wc * 32 + jt * 16 + g * 4;
      float4 o;
      o.x = acc[it][jt][0] + bo[nb4 + 0];
      o.y = acc[it][jt][1] + bo[nb4 + 1];
      o.z = acc[it][jt][2] + bo[nb4 + 2];
      o.w = acc[it][jt][3] + bo[nb4 + 3];
      *(float4*)(out + (size_t)R * 128 + nb4) = o;
    }
  }
}

extern "C" void kernel_launch(void* const* d_in, const int* in_sizes, int n_in,
                              void* d_out, int out_size, void* d_ws, size_t ws_size,
                              hipStream_t stream) {
  const float* act  = (const float*)d_in[0];
  const float* mask = (const float*)d_in[1];
  const float* ln_g = (const float*)d_in[2];
  const float* ln_b = (const float*)d_in[3];
  const float* wq   = (const float*)d_in[4];
  const float* wk   = (const float*)d_in[5];
  const float* wv   = (const float*)d_in[6];
  const float* w2d  = (const float*)d_in[7];
  const float* wg   = (const float*)d_in[8];
  const float* bg   = (const float*)d_in[9];
  const float* wo   = (const float*)d_in[10];
  const float* bo   = (const float*)d_in[11];

  char* p = (char*)d_ws;
  unsigned short* lnxb  = (unsigned short*)p;  p += (size_t)8388608 * 2;   // [65536][128] bf16
  float*          b2t   = (float*)p;           p += (size_t)262144 * 4;    // [4][j*256+i] f32
  unsigned short* qb    = (unsigned short*)p;  p += (size_t)8388608 * 2;   // [262144][32] bf16
  unsigned short* kb    = (unsigned short*)p;  p += (size_t)8388608 * 2;
  unsigned short* vb    = (unsigned short*)p;  p += (size_t)8388608 * 2;
  unsigned short* sgb   = (unsigned short*)p;  p += (size_t)8388608 * 2;   // gate, bf16
  unsigned short* aob   = (unsigned short*)p;  p += (size_t)8388608 * 2;   // [65536][128] bf16
  unsigned short* Wt4   = (unsigned short*)p;  p += (size_t)73728 * 2;     // [576][128] bf16
  unsigned short* Wto   = (unsigned short*)p;  p += (size_t)16384 * 2;
  float*          maskT = (float*)p;           p += (size_t)65536 * 4;     // [m][j] * 1e9
  float* out = (float*)d_out;

  hipLaunchKernelGGL(k_ln,    dim3(4704),   dim3(256), 0, stream,
                     act, ln_g, ln_b, wq, wk, wv, wg, w2d, wo, mask, lnxb, Wt4, Wto, maskT);
  hipLaunchKernelGGL(k_projg, dim3(512, 9), dim3(256), 0, stream, lnxb, Wt4, bg, qb, kb, vb, sgb, b2t);
  hipLaunchKernelGGL(k_attn,  dim3(512, 4), dim3(256), 0, stream, qb, kb, vb, sgb, b2t, maskT, aob);
  hipLaunchKernelGGL(k_outg,  dim3(512, 2), dim3(256), 0, stream, aob, Wto, bo, out);
}